// Round 5
// baseline (165.706 us; speedup 1.0000x reference)
//
#include <hip/hip_runtime.h>
#include <stdint.h>

typedef float  f32x4 __attribute__((ext_vector_type(4)));
typedef short  s16x8 __attribute__((ext_vector_type(8)));
typedef unsigned int u32;
typedef unsigned short u16;
typedef unsigned int u32x4 __attribute__((ext_vector_type(4)));

#define HID 768
#define OUTF 128
#define LQ 32
#define LD 256
#define BD 512
#define NSLAB 16   // 256 rows / 16 rows per slab

// pack two f32 -> two bf16 (round-to-nearest, ties away): 2 adds + 1 v_perm
__device__ __forceinline__ u32 pk_rna(float lo, float hi) {
    u32 a = __builtin_bit_cast(u32, lo) + 0x8000u;
    u32 b = __builtin_bit_cast(u32, hi) + 0x8000u;
    return __builtin_amdgcn_perm(b, a, 0x07060302u);  // {b.hi16, a.hi16}
}
__device__ __forceinline__ s16x8 cvt8(f32x4 lo, f32x4 hi) {
    u32x4 p;
    p[0] = pk_rna(lo[0], lo[1]);
    p[1] = pk_rna(lo[2], lo[3]);
    p[2] = pk_rna(hi[0], hi[1]);
    p[3] = pk_rna(hi[2], hi[3]);
    return __builtin_bit_cast(s16x8, p);
}
__device__ __forceinline__ u16 f2bf(float x) {
    return (u16)((__builtin_bit_cast(u32, x) + 0x8000u) >> 16);
}

// async global->LDS, 16B per lane; lds dest = wave-uniform base + lane*16
__device__ __forceinline__ void gl2lds16(const void* g, void* l) {
    __builtin_amdgcn_global_load_lds((const __attribute__((address_space(1))) void*)g,
                                     (__attribute__((address_space(3))) void*)l, 16, 0, 0);
}

// ---------------- kernel 0: W f32 -> bf16, lane-contiguous MFMA fragment layout ----
// Wb3 u16 index: ((kk*8 + cf)*64 + lane)*8 + j  <=>  W[f = cf*16 + (lane&15)][k = kk*32 + (lane>>4)*8 + j]
__global__ __launch_bounds__(256) void wconv(const float* __restrict__ W,
                                             u32* __restrict__ Wb3d) {
    int t = blockIdx.x * 256 + threadIdx.x;   // dword index 0..49151
    int j2   = t & 3;
    int lane = (t >> 2) & 63;
    int cf   = (t >> 8) & 7;
    int kk   = t >> 11;                       // 0..23
    int l15 = lane & 15, g4 = lane >> 4;
    int f = cf * 16 + l15;
    int k = kk * 32 + g4 * 8 + j2 * 2;
    const float* src = W + (size_t)f * HID + k;
    Wb3d[t] = pk_rna(src[0], src[1]);
}

// ---------------- kernel 1: Q projection + L2 norm -> bf16 ----------------
__global__ __launch_bounds__(256) void qproj(const float* __restrict__ qh,
                                             const u16* __restrict__ Wb3,
                                             u16* __restrict__ Qb) {
    const int b = blockIdx.x;
    const int tid = threadIdx.x;
    const int w = tid >> 6, lane = tid & 63, g = lane >> 4, l15 = lane & 15;

    f32x4 acc[2][2] = {};
    const float* A0 = qh + ((size_t)b * LQ + l15) * HID + g * 8;
    const float* A1 = A0 + 16 * HID;
    const u16* Bp = Wb3 + w * 1024 + lane * 8;   // cf0 = 2w

    for (int kk = 0; kk < 24; ++kk) {
        f32x4 x0 = *(const f32x4*)A0;
        f32x4 x1 = *(const f32x4*)(A0 + 4);
        f32x4 y0 = *(const f32x4*)A1;
        f32x4 y1 = *(const f32x4*)(A1 + 4);
        s16x8 b0 = *(const s16x8*)(Bp);
        s16x8 b1 = *(const s16x8*)(Bp + 512);
        s16x8 a0 = cvt8(x0, x1);
        s16x8 a1 = cvt8(y0, y1);
        acc[0][0] = __builtin_amdgcn_mfma_f32_16x16x32_bf16(a0, b0, acc[0][0], 0, 0, 0);
        acc[0][1] = __builtin_amdgcn_mfma_f32_16x16x32_bf16(a0, b1, acc[0][1], 0, 0, 0);
        acc[1][0] = __builtin_amdgcn_mfma_f32_16x16x32_bf16(a1, b0, acc[1][0], 0, 0, 0);
        acc[1][1] = __builtin_amdgcn_mfma_f32_16x16x32_bf16(a1, b1, acc[1][1], 0, 0, 0);
        A0 += 32; A1 += 32; Bp += 4096;
    }

    __shared__ float part[4][32];
    __shared__ float invl[32];
#pragma unroll
    for (int rf = 0; rf < 2; ++rf)
#pragma unroll
        for (int reg = 0; reg < 4; ++reg) {
            float ss = acc[rf][0][reg] * acc[rf][0][reg] + acc[rf][1][reg] * acc[rf][1][reg];
            ss += __shfl_xor(ss, 1); ss += __shfl_xor(ss, 2);
            ss += __shfl_xor(ss, 4); ss += __shfl_xor(ss, 8);
            if (l15 == 0) part[w][rf * 16 + g * 4 + reg] = ss;
        }
    __syncthreads();
    if (tid < 32) {
        float ss = part[0][tid] + part[1][tid] + part[2][tid] + part[3][tid];
        invl[tid] = 1.f / fmaxf(sqrtf(ss), 1e-12f);
    }
    __syncthreads();
#pragma unroll
    for (int rf = 0; rf < 2; ++rf)
#pragma unroll
        for (int cf = 0; cf < 2; ++cf)
#pragma unroll
            for (int reg = 0; reg < 4; ++reg) {
                int q = rf * 16 + g * 4 + reg;
                int f = w * 32 + cf * 16 + l15;
                Qb[(size_t)b * LQ * OUTF + q * OUTF + f] = f2bf(acc[rf][cf][reg] * invl[q]);
            }
}

// ---------------- kernel 2: D projection (streaming) -> raw bf16 frags + sumsq -----
// grid = 512 (one doc), block = 512 (8 waves). Slab = 16 rows = 48 KB contiguous,
// global_load_lds double-buffer, counted vmcnt(6). Wave w owns cols [16w,16w+16).
// Outputs: Dg[doc][slab][kq][lane][8] (u16, MFMA-B-operand order, UNNORMALIZED),
//          ssG[doc][256] (f32 row sum-of-squares).
__global__ __launch_bounds__(512, 2) void dproj(const float* __restrict__ dh,
                                                const u16* __restrict__ Wb3,
                                                u16* __restrict__ Dg,
                                                float* __restrict__ ssG) {
    const int bd = blockIdx.x;
    const int tid = threadIdx.x;
    const int w = tid >> 6, lane = tid & 63, g4 = lane >> 4, l15 = lane & 15;

    __shared__ __align__(16) float stg[2][12288];   // 2 x 48 KB
    __shared__ __align__(16) u16   outb[2048];      // 4 KB: [16 rows][128] bf16, XOR-swizzled
    __shared__ float nrm[8][16];

    const float* dh_doc = dh + (size_t)bd * LD * HID;

    // ----- issue slab 0 DMA immediately -----
    {
        float* dst = &stg[0][0];
#pragma unroll
        for (int t = 0; t < 6; ++t) {
            int rr = 2 * w + (t >= 3 ? 1 : 0);
            const char* g = (const char*)dh_doc +
                ((size_t)rr * 3072 + (t % 3) * 1024 + ((lane ^ (rr & 7)) << 4));
            char* l = (char*)dst + (w * 6 + t) * 1024;
            gl2lds16(g, l);
        }
    }

    // ----- B fragments (cols 16w..16w+16): preload to registers -----
    s16x8 Bf[24];
#pragma unroll
    for (int kk = 0; kk < 24; ++kk)
        Bf[kk] = *(const s16x8*)(Wb3 + (size_t)(kk * 8 + w) * 512 + lane * 8);

    const int xw = (l15 & 7) << 4;

    for (int s = 0; s < NSLAB; ++s) {
        // --- issue next slab DMA (stays in flight across barriers) ---
        if (s < NSLAB - 1) {
            float* dst = &stg[(s + 1) & 1][0];
            const char* gbase = (const char*)dh_doc + (size_t)(s + 1) * 16 * 3072;
#pragma unroll
            for (int t = 0; t < 6; ++t) {
                int rr = 2 * w + (t >= 3 ? 1 : 0);
                const char* g = gbase + ((size_t)rr * 3072 + (t % 3) * 1024 + ((lane ^ (rr & 7)) << 4));
                char* l = (char*)dst + (w * 6 + t) * 1024;
                gl2lds16(g, l);
            }
            asm volatile("s_waitcnt vmcnt(6) lgkmcnt(0)" ::: "memory");
        } else {
            asm volatile("s_waitcnt vmcnt(0) lgkmcnt(0)" ::: "memory");
        }
        __builtin_amdgcn_s_barrier();          // slab s landed for all waves; outb free
        __builtin_amdgcn_sched_barrier(0);

        // --- GEMM: 16 rows x 16 cols (this wave), K = 768 ---
        const char* Ab = (const char*)&stg[s & 1][0] + l15 * 3072;
        f32x4 acc = {};
#pragma unroll
        for (int kk = 0; kk < 24; ++kk) {
            int lo = (kk * 128 + g4 * 32) ^ xw;
            f32x4 alo = *(const f32x4*)(Ab + lo);
            f32x4 ahi = *(const f32x4*)(Ab + (lo ^ 16));
            s16x8 a = cvt8(alo, ahi);
            acc = __builtin_amdgcn_mfma_f32_16x16x32_bf16(a, Bf[kk], acc, 0, 0, 0);
        }

        // --- per-row partial sum of squares over this wave's 16 cols ---
#pragma unroll
        for (int reg = 0; reg < 4; ++reg) {
            float ss = acc[reg] * acc[reg];
            ss += __shfl_xor(ss, 1); ss += __shfl_xor(ss, 2);
            ss += __shfl_xor(ss, 4); ss += __shfl_xor(ss, 8);
            if (l15 == 0) nrm[w][g4 * 4 + reg] = ss;
        }

        // --- raw bf16 into swizzled LDS bounce ---
#pragma unroll
        for (int reg = 0; reg < 4; ++reg) {
            int row = g4 * 4 + reg;
            int off = (row * 256 + (w * 16 + l15) * 2) ^ ((row & 7) << 4);
            *(u16*)((char*)outb + off) = f2bf(acc[reg]);
        }
        asm volatile("s_waitcnt lgkmcnt(0)" ::: "memory");
        __builtin_amdgcn_s_barrier();
        __builtin_amdgcn_sched_barrier(0);

        // --- coalesced stores: D frags (4 KB) + row sumsq (64 B) ---
        if (tid < 256) {
            int kq = tid >> 6, lane2 = tid & 63;
            int drow = lane2 & 15, g42 = lane2 >> 4;
            int loff = (drow * 256 + kq * 64 + g42 * 16) ^ ((drow & 7) << 4);
            s16x8 v = *(const s16x8*)((const char*)outb + loff);
            *(s16x8*)(Dg + ((size_t)(bd * NSLAB + s) * 4 + kq) * 512 + lane2 * 8) = v;
        } else if (tid < 272) {
            int row = tid - 256;
            float t2 = 0.f;
#pragma unroll
            for (int ww = 0; ww < 8; ++ww) t2 += nrm[ww][row];
            ssG[(size_t)bd * LD + s * 16 + row] = t2;
        }
        // next iteration's first barrier orders outb reuse after this copy
    }
}

// ---------------- kernel 3: MaxSim score from frags -------------------------------
// grid = 512 (one doc), block = 256 (4 waves). Wave w handles slabs {w, w+4, w+8, w+12}.
__global__ __launch_bounds__(256, 4) void score(const int* __restrict__ ids,
                                                const int* __restrict__ skiplist,
                                                const u16* __restrict__ Dg,
                                                const float* __restrict__ ssG,
                                                const u16* __restrict__ Qb,
                                                float* __restrict__ out) {
    const int bd = blockIdx.x;
    const int tid = threadIdx.x;
    const int w = tid >> 6, lane = tid & 63, g4 = lane >> 4, l15 = lane & 15;

    __shared__ int sk[64];
    __shared__ float red[4][32];

    if (tid < 64) sk[tid] = skiplist[tid];
    __syncthreads();

    const u16* Qbb = Qb + (size_t)(bd >> 3) * LQ * OUTF;
    s16x8 Qf[2][4];
#pragma unroll
    for (int qf = 0; qf < 2; ++qf)
#pragma unroll
        for (int kq = 0; kq < 4; ++kq)
            Qf[qf][kq] = *(const s16x8*)(Qbb + (size_t)(qf * 16 + l15) * OUTF + kq * 32 + g4 * 8);

    float rmax[2][4];
#pragma unroll
    for (int qf = 0; qf < 2; ++qf)
#pragma unroll
        for (int r = 0; r < 4; ++r) rmax[qf][r] = -INFINITY;

#pragma unroll
    for (int si = 0; si < 4; ++si) {
        int s = si * 4 + w;
        // mask + inv for drow = l15 (per-lane scalars; C-cols are drow = lane&15)
        int id = ids[(size_t)bd * LD + s * 16 + l15];
        int keep = (id != 0);
#pragma unroll
        for (int j = 0; j < 64; ++j) keep &= (id != sk[j]);
        float ssv = ssG[(size_t)bd * LD + s * 16 + l15];
        float inv = 1.f / fmaxf(sqrtf(ssv), 1e-12f);

        const u16* dp = Dg + (size_t)(bd * NSLAB + s) * 2048 + lane * 8;
        f32x4 s2[2] = {};
#pragma unroll
        for (int kq = 0; kq < 4; ++kq) {
            s16x8 d = *(const s16x8*)(dp + kq * 512);
            s2[0] = __builtin_amdgcn_mfma_f32_16x16x32_bf16(Qf[0][kq], d, s2[0], 0, 0, 0);
            s2[1] = __builtin_amdgcn_mfma_f32_16x16x32_bf16(Qf[1][kq], d, s2[1], 0, 0, 0);
        }
        float scale = keep ? inv : 0.f;   // masked rows contribute -inf below
#pragma unroll
        for (int qf = 0; qf < 2; ++qf)
#pragma unroll
            for (int reg = 0; reg < 4; ++reg) {
                float v = keep ? s2[qf][reg] * scale : -INFINITY;
                rmax[qf][reg] = fmaxf(rmax[qf][reg], v);
            }
    }

    // reduce over drow classes (l15), publish per-wave q-maxima
#pragma unroll
    for (int qf = 0; qf < 2; ++qf)
#pragma unroll
        for (int reg = 0; reg < 4; ++reg) {
            float v = rmax[qf][reg];
            v = fmaxf(v, __shfl_xor(v, 1));
            v = fmaxf(v, __shfl_xor(v, 2));
            v = fmaxf(v, __shfl_xor(v, 4));
            v = fmaxf(v, __shfl_xor(v, 8));
            if (l15 == 0) red[w][qf * 16 + g4 * 4 + reg] = v;
        }
    __syncthreads();

    if (tid < 32) {
        float mx = fmaxf(fmaxf(red[0][tid], red[1][tid]), fmaxf(red[2][tid], red[3][tid]));
        mx += __shfl_xor(mx, 1); mx += __shfl_xor(mx, 2);
        mx += __shfl_xor(mx, 4); mx += __shfl_xor(mx, 8);
        mx += __shfl_xor(mx, 16);
        if (tid == 0) out[bd] = mx * (1.f / 32.f);
    }
}

extern "C" void kernel_launch(void* const* d_in, const int* in_sizes, int n_in,
                              void* d_out, int out_size, void* d_ws, size_t ws_size,
                              hipStream_t stream) {
    const float* q_hidden = (const float*)d_in[0];
    const float* d_hidden = (const float*)d_in[1];
    const int*   d_ids    = (const int*)d_in[2];
    const int*   skiplist = (const int*)d_in[3];
    const float* W        = (const float*)d_in[4];
    float* out = (float*)d_out;

    u16*   Wb3 = (u16*)d_ws;                          // 192 KB frag-layout W
    u16*   Qb  = (u16*)((char*)d_ws + 256 * 1024);    // 512 KB bf16 Q
    u16*   Dg  = (u16*)((char*)d_ws + 1024 * 1024);   // 33.5 MB raw bf16 D frags
    float* ssG = (float*)((char*)d_ws + 40 * 1024 * 1024);  // 512 KB row sumsq

    wconv<<<192, 256, 0, stream>>>(W, (u32*)Wb3);
    qproj<<<64, 256, 0, stream>>>(q_hidden, Wb3, Qb);
    dproj<<<BD, 512, 0, stream>>>(d_hidden, Wb3, Dg, ssG);
    score<<<BD, 256, 0, stream>>>(d_ids, skiplist, Dg, ssG, Qb, out);
}

// Round 7
// 104.792 us; speedup vs baseline: 1.5813x; 1.5813x over previous
//
#include <hip/hip_runtime.h>
#include <stdint.h>

typedef float  f32x4 __attribute__((ext_vector_type(4)));
typedef short  s16x8 __attribute__((ext_vector_type(8)));
typedef unsigned int u32;
typedef unsigned short u16;
typedef unsigned int u32x2 __attribute__((ext_vector_type(2)));

#define HID 768
#define OUTF 128
#define LQ 32
#define LD 256

// pack two f32 -> two bf16 (round-to-nearest, ties away)
__device__ __forceinline__ u32 pk_rna(float lo, float hi) {
    u32 a = __builtin_bit_cast(u32, lo) + 0x8000u;
    u32 b = __builtin_bit_cast(u32, hi) + 0x8000u;
    return __builtin_amdgcn_perm(b, a, 0x07060302u);  // {hi.bf16, lo.bf16}
}
__device__ __forceinline__ u16 f2bf(float x) {
    return (u16)((__builtin_bit_cast(u32, x) + 0x8000u) >> 16);
}
__device__ __forceinline__ s16x8 cvt8(f32x4 lo, f32x4 hi) {
    union { u32 u[4]; s16x8 v; } ua;
    ua.u[0] = pk_rna(lo[0], lo[1]);
    ua.u[1] = pk_rna(lo[2], lo[3]);
    ua.u[2] = pk_rna(hi[0], hi[1]);
    ua.u[3] = pk_rna(hi[2], hi[3]);
    return ua.v;
}

// ---------------- kernel 0: W f32 -> bf16, lane-contiguous MFMA fragment layout ----
// Wb3 u16 index: ((kk*8 + cf)*64 + lane)*8 + j  <=>  W[f=cf*16+(lane&15)][k=kk*32+(lane>>4)*8+j]
__global__ __launch_bounds__(256) void wconv(const float* __restrict__ W,
                                             u32* __restrict__ Wb3d) {
    int t = blockIdx.x * 256 + threadIdx.x;   // dword index 0..49151
    int j2   = t & 3;
    int lane = (t >> 2) & 63;
    int cf   = (t >> 8) & 7;
    int kk   = t >> 11;                       // 0..23
    int l15 = lane & 15, g4 = lane >> 4;
    int f = cf * 16 + l15;
    int k = kk * 32 + g4 * 8 + j2 * 2;
    const float* src = W + (size_t)f * HID + k;
    Wb3d[t] = pk_rna(src[0], src[1]);
}

// ---------------- kernel 1: Q projection + L2 norm -> bf16 ----------------
__global__ __launch_bounds__(256) void qproj(const float* __restrict__ qh,
                                             const u16* __restrict__ Wb3,
                                             u16* __restrict__ Qb) {
    const int b = blockIdx.x;
    const int tid = threadIdx.x;
    const int w = tid >> 6, lane = tid & 63, g = lane >> 4, l15 = lane & 15;

    f32x4 acc[2][2] = {};
    const float* A0 = qh + ((size_t)b * LQ + l15) * HID + g * 8;
    const float* A1 = A0 + 16 * HID;
    const u16* Bp = Wb3 + w * 1024 + lane * 8;   // cf0 = 2w

    for (int kk = 0; kk < 24; ++kk) {
        f32x4 x0 = *(const f32x4*)A0;
        f32x4 x1 = *(const f32x4*)(A0 + 4);
        f32x4 y0 = *(const f32x4*)A1;
        f32x4 y1 = *(const f32x4*)(A1 + 4);
        s16x8 b0 = *(const s16x8*)(Bp);
        s16x8 b1 = *(const s16x8*)(Bp + 512);
        s16x8 a0 = cvt8(x0, x1);
        s16x8 a1 = cvt8(y0, y1);
        acc[0][0] = __builtin_amdgcn_mfma_f32_16x16x32_bf16(a0, b0, acc[0][0], 0, 0, 0);
        acc[0][1] = __builtin_amdgcn_mfma_f32_16x16x32_bf16(a0, b1, acc[0][1], 0, 0, 0);
        acc[1][0] = __builtin_amdgcn_mfma_f32_16x16x32_bf16(a1, b0, acc[1][0], 0, 0, 0);
        acc[1][1] = __builtin_amdgcn_mfma_f32_16x16x32_bf16(a1, b1, acc[1][1], 0, 0, 0);
        A0 += 32; A1 += 32; Bp += 4096;
    }

    __shared__ float part[4][32];
    __shared__ float invl[32];
#pragma unroll
    for (int rf = 0; rf < 2; ++rf)
#pragma unroll
        for (int reg = 0; reg < 4; ++reg) {
            float ss = acc[rf][0][reg] * acc[rf][0][reg] + acc[rf][1][reg] * acc[rf][1][reg];
            ss += __shfl_xor(ss, 1); ss += __shfl_xor(ss, 2);
            ss += __shfl_xor(ss, 4); ss += __shfl_xor(ss, 8);
            if (l15 == 0) part[w][rf * 16 + g * 4 + reg] = ss;
        }
    __syncthreads();
    if (tid < 32) {
        float ss = part[0][tid] + part[1][tid] + part[2][tid] + part[3][tid];
        invl[tid] = 1.f / fmaxf(sqrtf(ss), 1e-12f);
    }
    __syncthreads();
#pragma unroll
    for (int rf = 0; rf < 2; ++rf)
#pragma unroll
        for (int cf = 0; cf < 2; ++cf)
#pragma unroll
            for (int reg = 0; reg < 4; ++reg) {
                int q = rf * 16 + g * 4 + reg;
                int f = w * 32 + cf * 16 + l15;
                Qb[(size_t)b * LQ * OUTF + q * OUTF + f] = f2bf(acc[rf][cf][reg] * invl[q]);
            }
}

// ---------------- kernel 2: fused D-projection + norm + mask + MaxSim --------------
// grid = 256 (docs bid, bid+256), block = 512 (8 waves). Slab = 16 rows.
// Staging: global->reg (dense 1KB/instr) -> cvt bf16 -> ds_write (24 KB/slab),
// double-buffered, 2-deep load pipeline, ONE barrier per slab.
// GEMM: wave w owns cols [16w,16w+16); A bf16 frags via swizzled ds_read_b128.
// Sim: waves 0-3 do q[0:16], waves 4-7 do q[16:32]; Q frags in registers.
__global__ __launch_bounds__(512, 2) void dmax(const float* __restrict__ dh,
                                               const int* __restrict__ ids,
                                               const int* __restrict__ skiplist,
                                               const u16* __restrict__ Wb3,
                                               const u16* __restrict__ Qb,
                                               float* __restrict__ out) {
    const int bid = blockIdx.x;
    const int tid = threadIdx.x;
    const int w = tid >> 6, lane = tid & 63, g4 = lane >> 4, l15 = lane & 15;
    const int qh_ = w >> 2;

    __shared__ __align__(16) u16 stg[2][12288];   // 2 x 24 KB bf16 [16 rows][768], 16B-XOR swz
    __shared__ __align__(16) u16 outb[2][2048];   // 2 x 4 KB raw D [16 rows][128], swz
    __shared__ float nrm[2][8][16];
    __shared__ float wsum[8];
    __shared__ int ms[512];
    __shared__ int sk[64];

    // staging thread constants: thread handles bf16 8B-units {tid+512i}
    const int va = tid, vb = tid + 512, vc = tid + 1024,
              vd = tid + 1536, ve = tid + 2048, vf = tid + 2560;
#define LADOF(v) (((v) / 192) * 1536 + (((((v) % 192)) * 8) ^ ((((v) / 192) & 7) << 4)))
    const int lad0 = LADOF(va), lad1 = LADOF(vb), lad2 = LADOF(vc),
              lad3 = LADOF(vd), lad4 = LADOF(ve), lad5 = LADOF(vf);

    const int swz = (l15 & 7) << 4, sw45 = swz & 48, sw6 = swz & 64;
    const int aoffE = l15 * 1536 + ((g4 * 16) ^ sw45) + sw6;        // + kkp*128 (even kk)
    const int aoffO = l15 * 1536 + ((g4 * 16) ^ sw45) + 64 - sw6;   // + kkp*128 (odd kk)
    const int doffE = l15 * 256 + ((g4 * 16) ^ sw45) + sw6;         // kq 0,2 (+128)
    const int doffO = l15 * 256 + ((g4 * 16) ^ sw45) + 64 - sw6;    // kq 1,3 (+128)

    f32x4 LA0, LA1, LA2, LA3, LA4, LA5, LB0, LB1, LB2, LB3, LB4, LB5;
    s16x8 Qr0, Qr1, Qr2, Qr3;
    float rmaxH[4] = {-INFINITY, -INFINITY, -INFINITY, -INFINITY};

#define SLABBASE(sab) ((const char*)dh + (size_t)(bid + (((sab) >> 4) << 8)) * 786432 \
                       + (size_t)((sab) & 15) * 49152)

#define LISSUE(sab, S) { const char* gb_ = SLABBASE(sab); \
    S##0 = *(const f32x4*)(gb_ + va * 16); S##1 = *(const f32x4*)(gb_ + vb * 16); \
    S##2 = *(const f32x4*)(gb_ + vc * 16); S##3 = *(const f32x4*)(gb_ + vd * 16); \
    S##4 = *(const f32x4*)(gb_ + ve * 16); S##5 = *(const f32x4*)(gb_ + vf * 16); }

#define WSTORE(P, S) { char* sb_ = (char*)&stg[P][0]; u32x2 p_; \
    p_[0] = pk_rna(S##0[0], S##0[1]); p_[1] = pk_rna(S##0[2], S##0[3]); *(u32x2*)(sb_ + lad0) = p_; \
    p_[0] = pk_rna(S##1[0], S##1[1]); p_[1] = pk_rna(S##1[2], S##1[3]); *(u32x2*)(sb_ + lad1) = p_; \
    p_[0] = pk_rna(S##2[0], S##2[1]); p_[1] = pk_rna(S##2[2], S##2[3]); *(u32x2*)(sb_ + lad2) = p_; \
    p_[0] = pk_rna(S##3[0], S##3[1]); p_[1] = pk_rna(S##3[2], S##3[3]); *(u32x2*)(sb_ + lad3) = p_; \
    p_[0] = pk_rna(S##4[0], S##4[1]); p_[1] = pk_rna(S##4[2], S##4[3]); *(u32x2*)(sb_ + lad4) = p_; \
    p_[0] = pk_rna(S##5[0], S##5[1]); p_[1] = pk_rna(S##5[2], S##5[3]); *(u32x2*)(sb_ + lad5) = p_; }

#define QLOAD(doc_) { const u16* qp_ = Qb + (size_t)((bid + (doc_) * 256) >> 3) * 4096 \
                      + (qh_ * 16 + l15) * 128 + g4 * 8; \
    Qr0 = *(const s16x8*)(qp_);      Qr1 = *(const s16x8*)(qp_ + 32); \
    Qr2 = *(const s16x8*)(qp_ + 64); Qr3 = *(const s16x8*)(qp_ + 96); }

#define GEMMN(P) { \
    const char* Ab_ = (const char*)&stg[P][0]; \
    f32x4 ac0_ = {}, ac1_ = {}; \
    _Pragma("unroll") for (int kkp = 0; kkp < 12; ++kkp) { \
        s16x8 ae_ = *(const s16x8*)(Ab_ + aoffE + kkp * 128); \
        s16x8 ao_ = *(const s16x8*)(Ab_ + aoffO + kkp * 128); \
        ac0_ = __builtin_amdgcn_mfma_f32_16x16x32_bf16(ae_, Bf[2 * kkp],     ac0_, 0, 0, 0); \
        ac1_ = __builtin_amdgcn_mfma_f32_16x16x32_bf16(ao_, Bf[2 * kkp + 1], ac1_, 0, 0, 0); \
    } \
    f32x4 aG_ = ac0_ + ac1_; \
    _Pragma("unroll") for (int rg = 0; rg < 4; ++rg) { \
        float ss_ = aG_[rg] * aG_[rg]; \
        ss_ += __shfl_xor(ss_, 1); ss_ += __shfl_xor(ss_, 2); \
        ss_ += __shfl_xor(ss_, 4); ss_ += __shfl_xor(ss_, 8); \
        if (l15 == 0) nrm[P][w][g4 * 4 + rg] = ss_; \
        int dr_ = g4 * 4 + rg; \
        int of_ = (dr_ * 256 + (w * 16 + l15) * 2) ^ ((dr_ & 7) << 4); \
        *(u16*)((char*)&outb[P][0] + of_) = f2bf(aG_[rg]); \
    } }

#define TAIL(P, sb) { \
    const char* Db_ = (const char*)&outb[P][0]; \
    s16x8 d0_ = *(const s16x8*)(Db_ + doffE); \
    s16x8 d1_ = *(const s16x8*)(Db_ + doffO); \
    s16x8 d2_ = *(const s16x8*)(Db_ + doffE + 128); \
    s16x8 d3_ = *(const s16x8*)(Db_ + doffO + 128); \
    f32x4 s2_ = {}; \
    s2_ = __builtin_amdgcn_mfma_f32_16x16x32_bf16(Qr0, d0_, s2_, 0, 0, 0); \
    s2_ = __builtin_amdgcn_mfma_f32_16x16x32_bf16(Qr1, d1_, s2_, 0, 0, 0); \
    s2_ = __builtin_amdgcn_mfma_f32_16x16x32_bf16(Qr2, d2_, s2_, 0, 0, 0); \
    s2_ = __builtin_amdgcn_mfma_f32_16x16x32_bf16(Qr3, d3_, s2_, 0, 0, 0); \
    float ssv_ = nrm[P][0][l15] + nrm[P][1][l15] + nrm[P][2][l15] + nrm[P][3][l15] \
               + nrm[P][4][l15] + nrm[P][5][l15] + nrm[P][6][l15] + nrm[P][7][l15]; \
    float inv_ = 1.f / fmaxf(sqrtf(ssv_), 1e-12f); \
    int keep_ = ms[(((sb) >> 4) << 8) + (((sb) & 15) << 4) + l15]; \
    _Pragma("unroll") for (int rg = 0; rg < 4; ++rg) { \
        float v_ = keep_ ? s2_[rg] * inv_ : -INFINITY; \
        rmaxH[rg] = fmaxf(rmaxH[rg], v_); } \
    if (((sb) & 15) == 15) { \
        float ps_ = 0.f; \
        _Pragma("unroll") for (int rg = 0; rg < 4; ++rg) { \
            float v_ = rmaxH[rg]; \
            v_ = fmaxf(v_, __shfl_xor(v_, 1)); v_ = fmaxf(v_, __shfl_xor(v_, 2)); \
            v_ = fmaxf(v_, __shfl_xor(v_, 4)); v_ = fmaxf(v_, __shfl_xor(v_, 8)); \
            ps_ += v_; rmaxH[rg] = -INFINITY; } \
        ps_ += __shfl_xor(ps_, 16); ps_ += __shfl_xor(ps_, 32); \
        if (lane == 0) wsum[w] = ps_; \
        asm volatile("s_waitcnt lgkmcnt(0)" ::: "memory"); \
        __builtin_amdgcn_s_barrier(); \
        if (tid == 0) out[bid + (((sb) >> 4) << 8)] = (wsum[0] + wsum[4]) * (1.f / 32.f); \
        if ((sb) == 15) { QLOAD(1); } \
    } }

    // ----- prologue -----
    LISSUE(0, LA);
    LISSUE(1, LB);

    // B fragments preload (cols 16w..16w+16, all K)
    s16x8 Bf[24];
#pragma unroll
    for (int kk = 0; kk < 24; ++kk)
        Bf[kk] = *(const s16x8*)(Wb3 + (size_t)(kk * 8 + w) * 512 + lane * 8);

    if (tid < 64) sk[tid] = skiplist[tid];
    asm volatile("s_waitcnt lgkmcnt(0)" ::: "memory");
    __builtin_amdgcn_s_barrier();
    {
        int d_ = tid >> 8, r_ = tid & 255;
        int id_ = ids[(size_t)(bid + d_ * 256) * 256 + r_];
        int keep_ = (id_ != 0);
#pragma unroll
        for (int j = 0; j < 64; ++j) keep_ &= (id_ != sk[j]);
        ms[tid] = keep_;
    }
    WSTORE(0, LA);
    QLOAD(0);
    asm volatile("s_waitcnt lgkmcnt(0)" ::: "memory");
    __builtin_amdgcn_s_barrier();

    // ----- main loop: 32 slabs (2 docs x 16), unrolled by 2 for static buffers -----
    for (int it = 0; it < 16; ++it) {
        const int sbE = 2 * it, sbO = 2 * it + 1;

        if (sbE + 2 < 32) LISSUE(sbE + 2, LA);
        WSTORE(1, LB);
        GEMMN(0);
        asm volatile("s_waitcnt lgkmcnt(0)" ::: "memory");
        __builtin_amdgcn_s_barrier();
        TAIL(0, sbE);

        if (sbO + 2 < 32) LISSUE(sbO + 2, LB);
        if (sbO + 1 < 32) WSTORE(0, LA);
        GEMMN(1);
        asm volatile("s_waitcnt lgkmcnt(0)" ::: "memory");
        __builtin_amdgcn_s_barrier();
        TAIL(1, sbO);
    }
}

extern "C" void kernel_launch(void* const* d_in, const int* in_sizes, int n_in,
                              void* d_out, int out_size, void* d_ws, size_t ws_size,
                              hipStream_t stream) {
    const float* q_hidden = (const float*)d_in[0];
    const float* d_hidden = (const float*)d_in[1];
    const int*   d_ids    = (const int*)d_in[2];
    const int*   skiplist = (const int*)d_in[3];
    const float* W        = (const float*)d_in[4];
    float* out = (float*)d_out;

    u16* Wb3 = (u16*)d_ws;                        // 192 KB frag-layout W (bf16)
    u16* Qb  = (u16*)((char*)d_ws + 256 * 1024);  // 512 KB bf16 normalized Q

    wconv<<<192, 256, 0, stream>>>(W, (u32*)Wb3);
    qproj<<<64, 256, 0, stream>>>(q_hidden, Wb3, Qb);
    dmax<<<256, 512, 0, stream>>>(d_hidden, d_ids, skiplist, Wb3, Qb, out);
}

// Round 8
// 103.213 us; speedup vs baseline: 1.6055x; 1.0153x over previous
//
#include <hip/hip_runtime.h>
#include <stdint.h>

typedef float  f32x4 __attribute__((ext_vector_type(4)));
typedef short  s16x8 __attribute__((ext_vector_type(8)));
typedef unsigned int u32;
typedef unsigned short u16;
typedef unsigned int u32x4 __attribute__((ext_vector_type(4)));

#define HID 768
#define OUTF 128
#define LQ 32
#define LD 256

// pack two f32 -> two bf16 (round-to-nearest, ties away)
__device__ __forceinline__ u32 pk_rna(float lo, float hi) {
    u32 a = __builtin_bit_cast(u32, lo) + 0x8000u;
    u32 b = __builtin_bit_cast(u32, hi) + 0x8000u;
    return __builtin_amdgcn_perm(b, a, 0x07060302u);  // {hi.bf16, lo.bf16}
}
__device__ __forceinline__ u16 f2bf(float x) {
    return (u16)((__builtin_bit_cast(u32, x) + 0x8000u) >> 16);
}
__device__ __forceinline__ s16x8 cvt8(f32x4 lo, f32x4 hi) {
    union { u32 u[4]; s16x8 v; } ua;
    ua.u[0] = pk_rna(lo[0], lo[1]);
    ua.u[1] = pk_rna(lo[2], lo[3]);
    ua.u[2] = pk_rna(hi[0], hi[1]);
    ua.u[3] = pk_rna(hi[2], hi[3]);
    return ua.v;
}

// ---------------- kernel 0: W f32 -> bf16, lane-contiguous MFMA fragment layout ----
__global__ __launch_bounds__(256) void wconv(const float* __restrict__ W,
                                             u32* __restrict__ Wb3d) {
    int t = blockIdx.x * 256 + threadIdx.x;   // dword index 0..49151
    int j2   = t & 3;
    int lane = (t >> 2) & 63;
    int cf   = (t >> 8) & 7;
    int kk   = t >> 11;                       // 0..23
    int l15 = lane & 15, g4 = lane >> 4;
    int f = cf * 16 + l15;
    int k = kk * 32 + g4 * 8 + j2 * 2;
    const float* src = W + (size_t)f * HID + k;
    Wb3d[t] = pk_rna(src[0], src[1]);
}

// ---------------- kernel 1: Q projection + L2 norm -> bf16 ----------------
__global__ __launch_bounds__(256) void qproj(const float* __restrict__ qh,
                                             const u16* __restrict__ Wb3,
                                             u16* __restrict__ Qb) {
    const int b = blockIdx.x;
    const int tid = threadIdx.x;
    const int w = tid >> 6, lane = tid & 63, g = lane >> 4, l15 = lane & 15;

    f32x4 acc[2][2] = {};
    const float* A0 = qh + ((size_t)b * LQ + l15) * HID + g * 8;
    const float* A1 = A0 + 16 * HID;
    const u16* Bp = Wb3 + w * 1024 + lane * 8;   // cf0 = 2w

    for (int kk = 0; kk < 24; ++kk) {
        f32x4 x0 = *(const f32x4*)A0;
        f32x4 x1 = *(const f32x4*)(A0 + 4);
        f32x4 y0 = *(const f32x4*)A1;
        f32x4 y1 = *(const f32x4*)(A1 + 4);
        s16x8 b0 = *(const s16x8*)(Bp);
        s16x8 b1 = *(const s16x8*)(Bp + 512);
        s16x8 a0 = cvt8(x0, x1);
        s16x8 a1 = cvt8(y0, y1);
        acc[0][0] = __builtin_amdgcn_mfma_f32_16x16x32_bf16(a0, b0, acc[0][0], 0, 0, 0);
        acc[0][1] = __builtin_amdgcn_mfma_f32_16x16x32_bf16(a0, b1, acc[0][1], 0, 0, 0);
        acc[1][0] = __builtin_amdgcn_mfma_f32_16x16x32_bf16(a1, b0, acc[1][0], 0, 0, 0);
        acc[1][1] = __builtin_amdgcn_mfma_f32_16x16x32_bf16(a1, b1, acc[1][1], 0, 0, 0);
        A0 += 32; A1 += 32; Bp += 4096;
    }

    __shared__ float part[4][32];
    __shared__ float invl[32];
#pragma unroll
    for (int rf = 0; rf < 2; ++rf)
#pragma unroll
        for (int reg = 0; reg < 4; ++reg) {
            float ss = acc[rf][0][reg] * acc[rf][0][reg] + acc[rf][1][reg] * acc[rf][1][reg];
            ss += __shfl_xor(ss, 1); ss += __shfl_xor(ss, 2);
            ss += __shfl_xor(ss, 4); ss += __shfl_xor(ss, 8);
            if (l15 == 0) part[w][rf * 16 + g * 4 + reg] = ss;
        }
    __syncthreads();
    if (tid < 32) {
        float ss = part[0][tid] + part[1][tid] + part[2][tid] + part[3][tid];
        invl[tid] = 1.f / fmaxf(sqrtf(ss), 1e-12f);
    }
    __syncthreads();
#pragma unroll
    for (int rf = 0; rf < 2; ++rf)
#pragma unroll
        for (int cf = 0; cf < 2; ++cf)
#pragma unroll
            for (int reg = 0; reg < 4; ++reg) {
                int q = rf * 16 + g * 4 + reg;
                int f = w * 32 + cf * 16 + l15;
                Qb[(size_t)b * LQ * OUTF + q * OUTF + f] = f2bf(acc[rf][cf][reg] * invl[q]);
            }
}

// ---------------- kernel 2: fused D-projection + norm + mask + MaxSim --------------
// grid = 256 (docs bid, bid+256), block = 512 (8 waves). Slab = 16 rows.
// 3-deep pipeline: LISSUE(s+3) at slab s; WSTORE(s+1) (3x ds_write_b128);
// GEMM wave w owns cols [16w,16w+16); TAIL only on waves 0,4 (redundant otherwise).
__global__ __launch_bounds__(512, 2) void dmax(const float* __restrict__ dh,
                                               const int* __restrict__ ids,
                                               const int* __restrict__ skiplist,
                                               const u16* __restrict__ Wb3,
                                               const u16* __restrict__ Qb,
                                               float* __restrict__ out) {
    const int bid = blockIdx.x;
    const int tid = threadIdx.x;
    const int w = tid >> 6, lane = tid & 63, g4 = lane >> 4, l15 = lane & 15;
    const int qh_ = w >> 2;

    __shared__ __align__(16) u16 stg[3][12288];   // 3 x 24 KB bf16 [16 rows][768], 16B-XOR swz
    __shared__ __align__(16) u16 outb[2][2048];   // 2 x 4 KB raw D [16 rows][128], swz
    __shared__ __align__(16) float nrm[2][16][8]; // [P][row][wave]
    __shared__ float wsum[8];
    __shared__ int ms[512];
    __shared__ int sk[64];

    // staging: thread t owns bf16 8B-unit pairs (2t,2t+1)+1024i, i=0..2
#define PADOF(v) (((v) / 192) * 1536 + (((((v) % 192)) * 8) ^ ((((v) / 192) & 7) << 4)))
    const int pad0 = PADOF(2 * tid), pad1 = PADOF(2 * tid + 1024), pad2 = PADOF(2 * tid + 2048);

    const int swz = (l15 & 7) << 4, sw45 = swz & 48, sw6 = swz & 64;
    const int aoffE = l15 * 1536 + ((g4 * 16) ^ sw45) + sw6;        // + kkp*128 (even kk)
    const int aoffO = l15 * 1536 + ((g4 * 16) ^ sw45) + 64 - sw6;   // + kkp*128 (odd kk)
    const int doffE = l15 * 256 + ((g4 * 16) ^ sw45) + sw6;         // kq 0,2 (+128)
    const int doffO = l15 * 256 + ((g4 * 16) ^ sw45) + 64 - sw6;    // kq 1,3 (+128)

    f32x4 LA0, LA1, LA2, LA3, LA4, LA5, LB0, LB1, LB2, LB3, LB4, LB5,
          LC0, LC1, LC2, LC3, LC4, LC5;
    s16x8 Qr0, Qr1, Qr2, Qr3;
    float rmaxH[4] = {-INFINITY, -INFINITY, -INFINITY, -INFINITY};

#define SLABBASE(sab) ((const char*)dh + (size_t)(bid + (((sab) >> 4) << 8)) * 786432 \
                       + (size_t)((sab) & 15) * 49152)

#define LISSUE(sab, S) { const char* gb_ = SLABBASE(sab) + 32 * tid; \
    S##0 = *(const f32x4*)(gb_);          S##1 = *(const f32x4*)(gb_ + 16); \
    S##2 = *(const f32x4*)(gb_ + 16384);  S##3 = *(const f32x4*)(gb_ + 16400); \
    S##4 = *(const f32x4*)(gb_ + 32768);  S##5 = *(const f32x4*)(gb_ + 32784); }

#define WSTORE(P, S) { char* sb_ = (char*)&stg[P][0]; u32x4 q_; \
    q_[0] = pk_rna(S##0[0], S##0[1]); q_[1] = pk_rna(S##0[2], S##0[3]); \
    q_[2] = pk_rna(S##1[0], S##1[1]); q_[3] = pk_rna(S##1[2], S##1[3]); \
    *(u32x4*)(sb_ + pad0) = q_; \
    q_[0] = pk_rna(S##2[0], S##2[1]); q_[1] = pk_rna(S##2[2], S##2[3]); \
    q_[2] = pk_rna(S##3[0], S##3[1]); q_[3] = pk_rna(S##3[2], S##3[3]); \
    *(u32x4*)(sb_ + pad1) = q_; \
    q_[0] = pk_rna(S##4[0], S##4[1]); q_[1] = pk_rna(S##4[2], S##4[3]); \
    q_[2] = pk_rna(S##5[0], S##5[1]); q_[3] = pk_rna(S##5[2], S##5[3]); \
    *(u32x4*)(sb_ + pad2) = q_; }

#define QLOAD(doc_) { const u16* qp_ = Qb + (size_t)((bid + (doc_) * 256) >> 3) * 4096 \
                      + (qh_ * 16 + l15) * 128 + g4 * 8; \
    Qr0 = *(const s16x8*)(qp_);      Qr1 = *(const s16x8*)(qp_ + 32); \
    Qr2 = *(const s16x8*)(qp_ + 64); Qr3 = *(const s16x8*)(qp_ + 96); }

#define GEMMN(P, s_) { \
    const char* Ab_ = (const char*)&stg[P][0]; \
    u16* ob_ = &outb[(s_) & 1][0]; \
    f32x4 ac0_ = {}, ac1_ = {}; \
    _Pragma("unroll") for (int kkp = 0; kkp < 12; ++kkp) { \
        s16x8 ae_ = *(const s16x8*)(Ab_ + aoffE + kkp * 128); \
        s16x8 ao_ = *(const s16x8*)(Ab_ + aoffO + kkp * 128); \
        ac0_ = __builtin_amdgcn_mfma_f32_16x16x32_bf16(ae_, Bf[2 * kkp],     ac0_, 0, 0, 0); \
        ac1_ = __builtin_amdgcn_mfma_f32_16x16x32_bf16(ao_, Bf[2 * kkp + 1], ac1_, 0, 0, 0); \
    } \
    f32x4 aG_ = ac0_ + ac1_; \
    _Pragma("unroll") for (int rg = 0; rg < 4; ++rg) { \
        float ss_ = aG_[rg] * aG_[rg]; \
        ss_ += __shfl_xor(ss_, 1); ss_ += __shfl_xor(ss_, 2); \
        ss_ += __shfl_xor(ss_, 4); ss_ += __shfl_xor(ss_, 8); \
        if (l15 == 0) nrm[(s_) & 1][g4 * 4 + rg][w] = ss_; \
        int dr_ = g4 * 4 + rg; \
        int of_ = (dr_ * 256 + (w * 16 + l15) * 2) ^ ((dr_ & 7) << 4); \
        *(u16*)((char*)ob_ + of_) = f2bf(aG_[rg]); \
    } }

#define TAIL(sb) { \
    if ((w & 3) == 0) { \
        const char* Db_ = (const char*)&outb[(sb) & 1][0]; \
        s16x8 d0_ = *(const s16x8*)(Db_ + doffE); \
        s16x8 d1_ = *(const s16x8*)(Db_ + doffO); \
        s16x8 d2_ = *(const s16x8*)(Db_ + doffE + 128); \
        s16x8 d3_ = *(const s16x8*)(Db_ + doffO + 128); \
        f32x4 s2_ = {}; \
        s2_ = __builtin_amdgcn_mfma_f32_16x16x32_bf16(Qr0, d0_, s2_, 0, 0, 0); \
        s2_ = __builtin_amdgcn_mfma_f32_16x16x32_bf16(Qr1, d1_, s2_, 0, 0, 0); \
        s2_ = __builtin_amdgcn_mfma_f32_16x16x32_bf16(Qr2, d2_, s2_, 0, 0, 0); \
        s2_ = __builtin_amdgcn_mfma_f32_16x16x32_bf16(Qr3, d3_, s2_, 0, 0, 0); \
        f32x4 n0_ = *(const f32x4*)&nrm[(sb) & 1][l15][0]; \
        f32x4 n1_ = *(const f32x4*)&nrm[(sb) & 1][l15][4]; \
        float ssv_ = (n0_[0] + n0_[1] + n0_[2] + n0_[3]) \
                   + (n1_[0] + n1_[1] + n1_[2] + n1_[3]); \
        float inv_ = 1.f / fmaxf(sqrtf(ssv_), 1e-12f); \
        int keep_ = ms[(((sb) >> 4) << 8) + (((sb) & 15) << 4) + l15]; \
        _Pragma("unroll") for (int rg = 0; rg < 4; ++rg) { \
            float v_ = keep_ ? s2_[rg] * inv_ : -INFINITY; \
            rmaxH[rg] = fmaxf(rmaxH[rg], v_); } \
    } \
    if (((sb) & 15) == 15) { \
        if ((w & 3) == 0) { \
            float ps_ = 0.f; \
            _Pragma("unroll") for (int rg = 0; rg < 4; ++rg) { \
                float v_ = rmaxH[rg]; \
                v_ = fmaxf(v_, __shfl_xor(v_, 1)); v_ = fmaxf(v_, __shfl_xor(v_, 2)); \
                v_ = fmaxf(v_, __shfl_xor(v_, 4)); v_ = fmaxf(v_, __shfl_xor(v_, 8)); \
                ps_ += v_; rmaxH[rg] = -INFINITY; } \
            ps_ += __shfl_xor(ps_, 16); ps_ += __shfl_xor(ps_, 32); \
            if (lane == 0) wsum[w] = ps_; \
            if ((sb) == 15) { QLOAD(1); } \
        } \
        asm volatile("s_waitcnt lgkmcnt(0)" ::: "memory"); \
        __builtin_amdgcn_s_barrier(); \
        if (tid == 0) out[bid + (((sb) >> 4) << 8)] = (wsum[0] + wsum[4]) * (1.f / 32.f); \
    } }

#define SLABSTEP(s_, PG_, PW_, RN_, RW_, doIssue_, doWr_) { \
    if (doIssue_) LISSUE((s_) + 3, RN_); \
    if (doWr_) WSTORE(PW_, RW_); \
    GEMMN(PG_, s_); \
    asm volatile("s_waitcnt lgkmcnt(0)" ::: "memory"); \
    __builtin_amdgcn_s_barrier(); \
    TAIL(s_); }

    // ----- prologue -----
    LISSUE(0, LA);
    LISSUE(1, LB);
    LISSUE(2, LC);

    s16x8 Bf[24];
#pragma unroll
    for (int kk = 0; kk < 24; ++kk)
        Bf[kk] = *(const s16x8*)(Wb3 + (size_t)(kk * 8 + w) * 512 + lane * 8);

    if (tid < 64) sk[tid] = skiplist[tid];
    asm volatile("s_waitcnt lgkmcnt(0)" ::: "memory");
    __builtin_amdgcn_s_barrier();
    {
        int d_ = tid >> 8, r_ = tid & 255;
        int id_ = ids[(size_t)(bid + d_ * 256) * 256 + r_];
        int keep_ = (id_ != 0);
#pragma unroll
        for (int j = 0; j < 64; ++j) keep_ &= (id_ != sk[j]);
        ms[tid] = keep_;
    }
    WSTORE(0, LA);
    if ((w & 3) == 0) { QLOAD(0); }
    asm volatile("s_waitcnt lgkmcnt(0)" ::: "memory");
    __builtin_amdgcn_s_barrier();

    // ----- main loop: 32 slabs (2 docs x 16), 3-buffer, unroll by 3 -----
    for (int j = 0; j < 10; ++j) {
        const int s0 = 3 * j;
        SLABSTEP(s0,     0, 1, LA, LB, true,        true);
        SLABSTEP(s0 + 1, 1, 2, LB, LC, true,        true);   // issues s0+4 <= 31
        SLABSTEP(s0 + 2, 2, 0, LC, LA, s0 + 5 < 32, true);
    }
    SLABSTEP(30, 0, 1, LA, LB, false, true);
    SLABSTEP(31, 1, 2, LB, LC, false, false);
}

extern "C" void kernel_launch(void* const* d_in, const int* in_sizes, int n_in,
                              void* d_out, int out_size, void* d_ws, size_t ws_size,
                              hipStream_t stream) {
    const float* q_hidden = (const float*)d_in[0];
    const float* d_hidden = (const float*)d_in[1];
    const int*   d_ids    = (const int*)d_in[2];
    const int*   skiplist = (const int*)d_in[3];
    const float* W        = (const float*)d_in[4];
    float* out = (float*)d_out;

    u16* Wb3 = (u16*)d_ws;                        // 192 KB frag-layout W (bf16)
    u16* Qb  = (u16*)((char*)d_ws + 256 * 1024);  // 512 KB bf16 normalized Q

    wconv<<<192, 256, 0, stream>>>(W, (u32*)Wb3);
    qproj<<<64, 256, 0, stream>>>(q_hidden, Wb3, Qb);
    dmax<<<256, 512, 0, stream>>>(d_hidden, d_ids, skiplist, Wb3, Qb, out);
}